// Round 14
// baseline (118.230 us; speedup 1.0000x reference)
//
#include <hip/hip_runtime.h>
#include <hip/hip_bf16.h>

typedef __attribute__((ext_vector_type(8))) short bf16x8;
typedef __attribute__((ext_vector_type(4))) float f32x4;

// RNE float -> bf16 bits
static __device__ __forceinline__ ushort f2b(float f) {
    unsigned u = __float_as_uint(f);
    return (ushort)((u + 0x7fffu + ((u >> 16) & 1u)) >> 16);
}

static __device__ __forceinline__ void gload16(const void* g, void* lds) {
    __builtin_amdgcn_global_load_lds(
        (const __attribute__((address_space(1))) unsigned int*)g,
        (__attribute__((address_space(3))) unsigned int*)lds, 16, 0, 0);
}

// pure compiler memory fence: no instruction emitted; memory ops (ds_read,
// global_load_lds) cannot be scheduled across it. Raw s_barrier alone is NOT
// an LLVM memory fence, so every barrier that orders LDS traffic is paired
// with one of these. Register-only MFMAs remain free to schedule.
static __device__ __forceinline__ void cfence() { asm volatile("" ::: "memory"); }

// ---------------------------------------------------------------------------
// prep: per (b,d) row of x[64][256][196]: mean-center, write bf16 into
// xc[64][256][256] (k=196..255 zero), var_d (+1e-7) per row for the trace.
// ---------------------------------------------------------------------------
__global__ __launch_bounds__(256) void prep_kernel(
    const float* __restrict__ x, ushort* __restrict__ xc, float* __restrict__ var)
{
    const int t = threadIdx.x, wv = t >> 6, l = t & 63;
    const int bid = blockIdx.x;
    const int x8 = bid & 7, rr = bid >> 3;
    const int dgrp = rr & 63, bgrp = rr >> 6;
    const int b = bgrp * 8 + x8;
    const int rowid = b * 256 + dgrp * 4 + wv;
    const float* xr = x + (size_t)rowid * 196;

    float x0 = xr[l];
    float x1 = xr[l + 64];
    float x2 = xr[l + 128];
    float x3 = (l < 4) ? xr[l + 192] : 0.0f;

    float s1 = x0 + x1 + x2 + x3;
    float s2 = x0*x0 + x1*x1 + x2*x2 + x3*x3;
    #pragma unroll
    for (int off = 32; off; off >>= 1) {
        s1 += __shfl_xor(s1, off);
        s2 += __shfl_xor(s2, off);
    }
    const float mean = s1 * (1.0f / 196.0f);
    if (l == 0) var[rowid] = s2 * (1.0f / 196.0f) - mean * mean + 1e-7f;

    ushort* xcr = xc + (size_t)rowid * 256;
    xcr[l]       = f2b(x0 - mean);
    xcr[l + 64]  = f2b(x1 - mean);
    xcr[l + 128] = f2b(x2 - mean);
    xcr[l + 192] = (l < 4) ? f2b(x3 - mean) : (ushort)0;   // zero pad 196..255
}

// ---------------------------------------------------------------------------
// Batched NT GEMM on symmetric operands. 128x128 tile (2 blocks/CU, 64 KB),
// K=256 as 8 steps of BK=32, 4-slot LDS ring, PREFETCH DEPTH 3 (r10 schedule):
// steady s_waitcnt vmcnt(12) (3 steps x 4 loads in flight); tail 8/4/0.
// Safety: ds_reads are confined between the barriers by cfence() pairs —
// slot s&3 is rewritten by the stage issued in step s+1, which other waves
// issue only after passing step s's closing barrier; our reads are issued
// before it. 4 waves (2x2), 64x64/wave: 16 MFMA : 8 ds_read_b128 per step.
// MODE 0: cov  : C = Y0 = (acc/196 + 1e-7 I)/trace[b];  C2 = 1.5I - 0.5*Y0
// MODE 1: T    : C = 1.5I - 0.5*acc
// MODE 2: pair : half grid: C = A*Bt^T; other half: C2 = A2*Bt^T
// MODE 3: tri  : lower-tri of acc*sqrt(trace[b]) -> C (3 tiles of 128x128)
// MODE 4: plain: C = acc
// XCD-pinned: blockIdx%8 == batch%8 for every mode.
// ---------------------------------------------------------------------------
template<int MODE>
__global__ __launch_bounds__(256) void gemm_ns(
    const ushort* __restrict__ A, const ushort* __restrict__ A2,
    const ushort* __restrict__ Bt,
    ushort* __restrict__ C, ushort* __restrict__ C2,
    const float* __restrict__ var)
{
    __shared__ ushort As[4][128][32];   // 32 KB ring (8 KB/step)
    __shared__ ushort Bs[4][128][32];   // 32 KB ring
    __shared__ float tr_s[4];

    const int bid = blockIdx.x, x8 = bid & 7;
    int b, i0, j0;
    bool useA2 = false;
    if (MODE == 2) {
        const int tt = (bid >> 3) & 3;
        useA2 = ((bid >> 5) & 1) != 0;
        b = (bid >> 6) * 8 + x8;
        i0 = (tt >> 1) * 128; j0 = (tt & 1) * 128;
    } else if (MODE == 3) {
        const int rr = bid >> 3, t3 = rr % 3;
        b = (rr / 3) * 8 + x8;
        i0 = (t3 == 0) ? 0 : 128;
        j0 = (t3 == 2) ? 128 : 0;
    } else {
        const int tt = (bid >> 3) & 3;
        b = (bid >> 5) * 8 + x8;
        i0 = (tt >> 1) * 128; j0 = (tt & 1) * 128;
    }
    const ushort* Ab  = (useA2 ? A2 : A) + (size_t)b * 65536;
    const ushort* Btb = Bt + (size_t)b * 65536;

    const int t = threadIdx.x, wv = t >> 6, l = t & 63;
    const int li = l & 15, hi = l >> 4;
    const int wr = wv >> 1, wc = wv & 1;
    // staging: r0/c0 give a lane-linear [64][32] cover per 256 threads
    const int r0 = t >> 2;             // 0..63
    const int c0 = (t & 3) * 8;        // col offset in elements

    // per-batch trace reduction first (its wait drains nothing else)
    float trace = 0.f;
    if (MODE == 0 || MODE == 3) {
        float v = var[b * 256 + t];
        #pragma unroll
        for (int off = 32; off; off >>= 1) v += __shfl_xor(v, off);
        if (l == 0) tr_s[wv] = v;
    }

#define GSTAGE(s) do {                                                          \
    const int r_ = (s) & 3;                                                     \
    const int kk = (s) * 32;                                                    \
    gload16(Ab  + (size_t)(i0 + r0) * 256 + kk + c0,      &As[r_][r0][c0]);     \
    gload16(Ab  + (size_t)(i0 + 64 + r0) * 256 + kk + c0, &As[r_][64 + r0][c0]);\
    gload16(Btb + (size_t)(j0 + r0) * 256 + kk + c0,      &Bs[r_][r0][c0]);     \
    gload16(Btb + (size_t)(j0 + 64 + r0) * 256 + kk + c0, &Bs[r_][64 + r0][c0]);\
} while (0)

    GSTAGE(0); GSTAGE(1); GSTAGE(2);

    f32x4 acc[4][4];
    #pragma unroll
    for (int m = 0; m < 4; ++m)
        #pragma unroll
        for (int n = 0; n < 4; ++n) acc[m][n] = (f32x4){0.f, 0.f, 0.f, 0.f};

    #pragma unroll
    for (int s = 0; s < 8; ++s) {
        if (s < 5) GSTAGE(s + 3);
        // wait for step s's loads: 3 newer steps (12 gloads) may stay in flight
        if (s < 5)       asm volatile("s_waitcnt vmcnt(12)" ::: "memory");
        else if (s == 5) asm volatile("s_waitcnt vmcnt(8)" ::: "memory");
        else if (s == 6) asm volatile("s_waitcnt vmcnt(4)" ::: "memory");
        else             asm volatile("s_waitcnt vmcnt(0)" ::: "memory");
        __builtin_amdgcn_s_barrier();          // all waves' step-s loads landed
        cfence();                              // ds_reads cannot hoist above

        const int r = s & 3;
        bf16x8 af[4], bfr[4];
        #pragma unroll
        for (int m = 0; m < 4; ++m)
            af[m] = *(const bf16x8*)&As[r][wr * 64 + m * 16 + li][hi * 8];
        #pragma unroll
        for (int n = 0; n < 4; ++n)
            bfr[n] = *(const bf16x8*)&Bs[r][wc * 64 + n * 16 + li][hi * 8];
        #pragma unroll
        for (int m = 0; m < 4; ++m)
            #pragma unroll
            for (int n = 0; n < 4; ++n)
                acc[m][n] = __builtin_amdgcn_mfma_f32_16x16x32_bf16(
                    af[m], bfr[n], acc[m][n], 0, 0, 0);

        cfence();                              // ds_reads cannot sink below
        __builtin_amdgcn_s_barrier();          // releases slot for stage s+4
    }
#undef GSTAGE

    if (MODE == 0 || MODE == 3) trace = tr_s[0] + tr_s[1] + tr_s[2] + tr_s[3];

    if (MODE == 3) {
        const float sc = sqrtf(trace);
        ushort* trib = C + (size_t)b * 32896;
        #pragma unroll
        for (int m = 0; m < 4; ++m)
            #pragma unroll
            for (int n = 0; n < 4; ++n)
                #pragma unroll
                for (int r = 0; r < 4; ++r) {
                    const int gi = i0 + wr * 64 + m * 16 + hi * 4 + r;
                    const int gj = j0 + wc * 64 + n * 16 + li;
                    if (gj <= gi)
                        trib[(gi * (gi + 1)) / 2 + gj] = f2b(acc[m][n][r] * sc);
                }
    } else {
        const float invtr = (MODE == 0) ? (1.0f / trace) : 0.0f;
        ushort* Cb  = ((MODE == 2 && useA2) ? C2 : C) + (size_t)b * 65536;
        ushort* C2b = (MODE == 0) ? (C2 + (size_t)b * 65536) : nullptr;
        #pragma unroll
        for (int m = 0; m < 4; ++m)
            #pragma unroll
            for (int n = 0; n < 4; ++n)
                #pragma unroll
                for (int r = 0; r < 4; ++r) {
                    const int gi = i0 + wr * 64 + m * 16 + hi * 4 + r;
                    const int gj = j0 + wc * 64 + n * 16 + li;
                    const float v = acc[m][n][r];
                    const size_t idx = (size_t)gi * 256 + gj;
                    if (MODE == 0) {
                        float y0 = (v * (1.0f / 196.0f) + ((gi == gj) ? 1e-7f : 0.0f)) * invtr;
                        Cb[idx]  = f2b(y0);
                        C2b[idx] = f2b(((gi == gj) ? 1.5f : 0.0f) - 0.5f * y0);
                    } else if (MODE == 1) {
                        Cb[idx] = f2b(((gi == gj) ? 1.5f : 0.0f) - 0.5f * v);
                    } else {
                        Cb[idx] = f2b(v);
                    }
                }
    }
}

// ---------------------------------------------------------------------------
// FC: partial[split][64][384] = tri[64][K] * W[365][K]^T over this split's K.
// Counted-vmcnt streaming pipeline, 4-deep slab ring, 3 steps in flight,
// cfence-paired barriers, CORRECT tail countdown 9/6/3/0 (previous rounds'
// flat vmcnt(9) under-waited the last 3 steps).
// 128 K-splits (768 blocks = 3/CU at 48 KB): 1028 steps of 32 = 4*9 + 124*8.
// ---------------------------------------------------------------------------
__global__ __launch_bounds__(256) void fc_gemm(
    const ushort* __restrict__ tri, const float* __restrict__ W,
    float* __restrict__ partial)
{
    __shared__ ushort Asl[4][64][32];   // 16 KB
    __shared__ float  Wsl[4][64][32];   // 32 KB

    const int ntile = blockIdx.x;              // 0..5
    const int split = blockIdx.y;              // 0..127
    const int steps = 8 + (split < 4 ? 1 : 0);
    const int step0 = split * 8 + (split < 4 ? split : 4);

    const int tid = threadIdx.x, wv = tid >> 6, l = tid & 63;
    const int li = l & 15, hi = l >> 4;

    const int arow = tid >> 2, aseg = tid & 3;            // A: 1 granule/thread
    const int wrow0 = tid >> 3, wseg = tid & 7;           // W: 2 granules/thread
    const int wrow1 = 32 + (tid >> 3);
    const int wcl0 = min(ntile * 64 + wrow0, 364);
    const int wcl1 = min(ntile * 64 + wrow1, 364);

#define FSTAGE(s) do {                                                          \
    const int kk_ = (step0 + (s)) * 32;                                         \
    const int r_ = (s) & 3;                                                     \
    gload16(tri + (size_t)arow * 32896 + kk_ + aseg * 8,                        \
            &Asl[r_][arow][aseg * 8]);                                          \
    gload16(W + (size_t)wcl0 * 32896 + kk_ + wseg * 4,                          \
            &Wsl[r_][wrow0][wseg * 4]);                                         \
    gload16(W + (size_t)wcl1 * 32896 + kk_ + wseg * 4,                          \
            &Wsl[r_][wrow1][wseg * 4]);                                         \
} while (0)

    FSTAGE(0); FSTAGE(1); FSTAGE(2);

    f32x4 acc[4];
    #pragma unroll
    for (int m = 0; m < 4; ++m) acc[m] = (f32x4){0.f, 0.f, 0.f, 0.f};

    for (int s = 0; s < steps; ++s) {
        if (s + 3 < steps) {
            FSTAGE(s + 3);
            asm volatile("s_waitcnt vmcnt(9)" ::: "memory");
        } else if (s + 2 < steps) {
            asm volatile("s_waitcnt vmcnt(6)" ::: "memory");
        } else if (s + 1 < steps) {
            asm volatile("s_waitcnt vmcnt(3)" ::: "memory");
        } else {
            asm volatile("s_waitcnt vmcnt(0)" ::: "memory");
        }
        __builtin_amdgcn_s_barrier();
        cfence();

        const int r = s & 3;
        const float4 wf0 = *(const float4*)&Wsl[r][wv * 16 + li][hi * 8];
        const float4 wf1 = *(const float4*)&Wsl[r][wv * 16 + li][hi * 8 + 4];
        bf16x8 bfr;
        bfr[0] = (short)f2b(wf0.x); bfr[1] = (short)f2b(wf0.y);
        bfr[2] = (short)f2b(wf0.z); bfr[3] = (short)f2b(wf0.w);
        bfr[4] = (short)f2b(wf1.x); bfr[5] = (short)f2b(wf1.y);
        bfr[6] = (short)f2b(wf1.z); bfr[7] = (short)f2b(wf1.w);

        bf16x8 af[4];
        #pragma unroll
        for (int m = 0; m < 4; ++m)
            af[m] = *(const bf16x8*)&Asl[r][m * 16 + li][hi * 8];
        #pragma unroll
        for (int m = 0; m < 4; ++m)
            acc[m] = __builtin_amdgcn_mfma_f32_16x16x32_bf16(af[m], bfr, acc[m], 0, 0, 0);

        cfence();
        __builtin_amdgcn_s_barrier();
    }
#undef FSTAGE

    #pragma unroll
    for (int m = 0; m < 4; ++m)
        #pragma unroll
        for (int rr = 0; rr < 4; ++rr) {
            const int i = m * 16 + hi * 4 + rr;          // batch
            const int j = ntile * 64 + wv * 16 + li;     // class (<384)
            partial[((size_t)split * 64 + i) * 384 + j] = acc[m][rr];
        }
}

__global__ void fc_reduce(const float* __restrict__ partial,
                          const float* __restrict__ bias, float* __restrict__ out)
{
    const int idx = blockIdx.x * 256 + threadIdx.x;
    if (idx >= 64 * 365) return;
    const int b = idx / 365, n = idx % 365;
    float s = bias[n];
    #pragma unroll 4
    for (int sp = 0; sp < 128; ++sp)
        s += partial[((size_t)sp * 64 + b) * 384 + n];
    out[idx] = s;
}

// ---------------------------------------------------------------------------
extern "C" void kernel_launch(void* const* d_in, const int* in_sizes, int n_in,
                              void* d_out, int out_size, void* d_ws, size_t ws_size,
                              hipStream_t stream)
{
    (void)in_sizes; (void)n_in; (void)out_size; (void)ws_size;
    const float* x   = (const float*)d_in[0];
    const float* fcw = (const float*)d_in[1];
    const float* fcb = (const float*)d_in[2];
    float* out = (float*)d_out;
    char* ws = (char*)d_ws;

    const size_t MS = (size_t)64 * 256 * 256 * 2;   // 8 MiB per matrix buffer
    ushort* w0 = (ushort*)(ws + 0 * MS);
    ushort* w1 = (ushort*)(ws + 1 * MS);
    ushort* w2 = (ushort*)(ws + 2 * MS);
    ushort* w3 = (ushort*)(ws + 3 * MS);
    ushort* w4 = (ushort*)(ws + 4 * MS);
    ushort* xc = (ushort*)(ws + 5 * MS);                     // 8 MiB (padded K=256)
    float*  var    = (float*)(ws + 6 * MS);                  // 65,536 B
    ushort* tri    = (ushort*)(ws + 6 * MS + 131072);        // 4,210,688 B
    float*  partial= (float*)(ws + 6 * MS + 131072 + 4210688);  // 12.6 MB

    prep_kernel<<<4096, 256, 0, stream>>>(x, xc, var);

    // cov: Y0 -> w0, T0 -> w1  (Z1 = T0)
    gemm_ns<0><<<256, 256, 0, stream>>>(xc, nullptr, xc, w0, w1, var);
    // Y1 = Y0*T0 -> w2
    gemm_ns<4><<<256, 256, 0, stream>>>(w0, nullptr, w1, w2, nullptr, nullptr);
    // iter2 (Y=w2, Z=w1): T -> w0 ; Y2 -> w3 ; Z2 -> w4
    gemm_ns<1><<<256, 256, 0, stream>>>(w1, nullptr, w2, w0, nullptr, nullptr);
    gemm_ns<2><<<512, 256, 0, stream>>>(w2, w1, w0, w3, w4, nullptr);
    // iter3 (Y=w3, Z=w4): T -> w0 ; Y3 -> w1 ; Z3 -> w2
    gemm_ns<1><<<256, 256, 0, stream>>>(w4, nullptr, w3, w0, nullptr, nullptr);
    gemm_ns<2><<<512, 256, 0, stream>>>(w3, w4, w0, w1, w2, nullptr);
    // iter4 (Y=w1, Z=w2): T -> w0 ; Y4 -> w3 ; Z4 -> w4
    gemm_ns<1><<<256, 256, 0, stream>>>(w2, nullptr, w1, w0, nullptr, nullptr);
    gemm_ns<2><<<512, 256, 0, stream>>>(w1, w2, w0, w3, w4, nullptr);
    // iter5 (Y=w3, Z=w4): T -> w0 ; tri(Y4*T5*sqrt(trace)) -> tri
    gemm_ns<1><<<256, 256, 0, stream>>>(w4, nullptr, w3, w0, nullptr, nullptr);
    gemm_ns<3><<<192, 256, 0, stream>>>(w3, nullptr, w0, tri, nullptr, var);

    fc_gemm<<<dim3(6, 128), 256, 0, stream>>>(tri, fcw, partial);
    fc_reduce<<<(64 * 365 + 255) / 256, 256, 0, stream>>>(partial, fcb, out);
}

// Round 15
// 112.614 us; speedup vs baseline: 1.0499x; 1.0499x over previous
//
#include <hip/hip_runtime.h>
#include <hip/hip_bf16.h>

typedef __attribute__((ext_vector_type(8))) short bf16x8;
typedef __attribute__((ext_vector_type(4))) float f32x4;

// RNE float -> bf16 bits
static __device__ __forceinline__ ushort f2b(float f) {
    unsigned u = __float_as_uint(f);
    return (ushort)((u + 0x7fffu + ((u >> 16) & 1u)) >> 16);
}

static __device__ __forceinline__ void gload16(const void* g, void* lds) {
    __builtin_amdgcn_global_load_lds(
        (const __attribute__((address_space(1))) unsigned int*)g,
        (__attribute__((address_space(3))) unsigned int*)lds, 16, 0, 0);
}

// pure compiler memory fence: no instruction emitted; memory ops (ds_read,
// global_load_lds) cannot be scheduled across it. Raw s_barrier alone is NOT
// an LLVM memory fence, so every barrier that orders LDS traffic is paired
// with one of these. Register-only MFMAs remain free to schedule.
static __device__ __forceinline__ void cfence() { asm volatile("" ::: "memory"); }

// ---------------------------------------------------------------------------
// prep: per (b,d) row of x[64][256][196]: mean-center, write bf16 into
// xc[64][256][256] (k=196..255 zero), var_d (+1e-7) per row for the trace.
// ---------------------------------------------------------------------------
__global__ __launch_bounds__(256) void prep_kernel(
    const float* __restrict__ x, ushort* __restrict__ xc, float* __restrict__ var)
{
    const int t = threadIdx.x, wv = t >> 6, l = t & 63;
    const int bid = blockIdx.x;
    const int x8 = bid & 7, rr = bid >> 3;
    const int dgrp = rr & 63, bgrp = rr >> 6;
    const int b = bgrp * 8 + x8;
    const int rowid = b * 256 + dgrp * 4 + wv;
    const float* xr = x + (size_t)rowid * 196;

    float x0 = xr[l];
    float x1 = xr[l + 64];
    float x2 = xr[l + 128];
    float x3 = (l < 4) ? xr[l + 192] : 0.0f;

    float s1 = x0 + x1 + x2 + x3;
    float s2 = x0*x0 + x1*x1 + x2*x2 + x3*x3;
    #pragma unroll
    for (int off = 32; off; off >>= 1) {
        s1 += __shfl_xor(s1, off);
        s2 += __shfl_xor(s2, off);
    }
    const float mean = s1 * (1.0f / 196.0f);
    if (l == 0) var[rowid] = s2 * (1.0f / 196.0f) - mean * mean + 1e-7f;

    ushort* xcr = xc + (size_t)rowid * 256;
    xcr[l]       = f2b(x0 - mean);
    xcr[l + 64]  = f2b(x1 - mean);
    xcr[l + 128] = f2b(x2 - mean);
    xcr[l + 192] = (l < 4) ? f2b(x3 - mean) : (ushort)0;   // zero pad 196..255
}

// ---------------------------------------------------------------------------
// Batched NT GEMM on symmetric operands. 128x128 tile (2 blocks/CU, 64 KB),
// K=256 as 8 steps of BK=32, 4-slot LDS ring, PREFETCH DEPTH 3:
// steady s_waitcnt vmcnt(12) (3 steps x 4 loads in flight); tail 8/4/0.
// Safety: cfence() pairs confine ds_reads between the barriers; the stage
// issued in step s+1 that overwrites step-s's slot cannot hoist above the
// closing barrier (cfence before it), and reads cannot sink below it.
// 4 waves (2x2), 64x64/wave: 16 MFMA : 8 ds_read_b128 per step.
// MODE 0: cov  : C = Y0 = (acc/196 + 1e-7 I)/trace[b];  C2 = 1.5I - 0.5*Y0
// MODE 1: T    : C = 1.5I - 0.5*acc
// MODE 2: pair : half grid: C = A*Bt^T; other half: C2 = A2*Bt^T
// MODE 3: tri  : lower-tri of acc*sqrt(trace[b]) -> C (3 tiles of 128x128)
// MODE 4: plain: C = acc
// XCD-pinned: blockIdx%8 == batch%8 for every mode.
// ---------------------------------------------------------------------------
template<int MODE>
__global__ __launch_bounds__(256) void gemm_ns(
    const ushort* __restrict__ A, const ushort* __restrict__ A2,
    const ushort* __restrict__ Bt,
    ushort* __restrict__ C, ushort* __restrict__ C2,
    const float* __restrict__ var)
{
    __shared__ ushort As[4][128][32];   // 32 KB ring (8 KB/step)
    __shared__ ushort Bs[4][128][32];   // 32 KB ring
    __shared__ float tr_s[4];

    const int bid = blockIdx.x, x8 = bid & 7;
    int b, i0, j0;
    bool useA2 = false;
    if (MODE == 2) {
        const int tt = (bid >> 3) & 3;
        useA2 = ((bid >> 5) & 1) != 0;
        b = (bid >> 6) * 8 + x8;
        i0 = (tt >> 1) * 128; j0 = (tt & 1) * 128;
    } else if (MODE == 3) {
        const int rr = bid >> 3, t3 = rr % 3;
        b = (rr / 3) * 8 + x8;
        i0 = (t3 == 0) ? 0 : 128;
        j0 = (t3 == 2) ? 128 : 0;
    } else {
        const int tt = (bid >> 3) & 3;
        b = (bid >> 5) * 8 + x8;
        i0 = (tt >> 1) * 128; j0 = (tt & 1) * 128;
    }
    const ushort* Ab  = (useA2 ? A2 : A) + (size_t)b * 65536;
    const ushort* Btb = Bt + (size_t)b * 65536;

    const int t = threadIdx.x, wv = t >> 6, l = t & 63;
    const int li = l & 15, hi = l >> 4;
    const int wr = wv >> 1, wc = wv & 1;
    // staging: r0/c0 give a lane-linear [64][32] cover per 256 threads
    const int r0 = t >> 2;             // 0..63
    const int c0 = (t & 3) * 8;        // col offset in elements

    // per-batch trace reduction first (its wait drains nothing else)
    float trace = 0.f;
    if (MODE == 0 || MODE == 3) {
        float v = var[b * 256 + t];
        #pragma unroll
        for (int off = 32; off; off >>= 1) v += __shfl_xor(v, off);
        if (l == 0) tr_s[wv] = v;
    }

#define GSTAGE(s) do {                                                          \
    const int r_ = (s) & 3;                                                     \
    const int kk = (s) * 32;                                                    \
    gload16(Ab  + (size_t)(i0 + r0) * 256 + kk + c0,      &As[r_][r0][c0]);     \
    gload16(Ab  + (size_t)(i0 + 64 + r0) * 256 + kk + c0, &As[r_][64 + r0][c0]);\
    gload16(Btb + (size_t)(j0 + r0) * 256 + kk + c0,      &Bs[r_][r0][c0]);     \
    gload16(Btb + (size_t)(j0 + 64 + r0) * 256 + kk + c0, &Bs[r_][64 + r0][c0]);\
} while (0)

    GSTAGE(0); GSTAGE(1); GSTAGE(2);

    f32x4 acc[4][4];
    #pragma unroll
    for (int m = 0; m < 4; ++m)
        #pragma unroll
        for (int n = 0; n < 4; ++n) acc[m][n] = (f32x4){0.f, 0.f, 0.f, 0.f};

    #pragma unroll
    for (int s = 0; s < 8; ++s) {
        if (s < 5) GSTAGE(s + 3);
        // wait for step s's loads: 3 newer steps (12 gloads) may stay in flight
        if (s < 5)       asm volatile("s_waitcnt vmcnt(12)" ::: "memory");
        else if (s == 5) asm volatile("s_waitcnt vmcnt(8)" ::: "memory");
        else if (s == 6) asm volatile("s_waitcnt vmcnt(4)" ::: "memory");
        else             asm volatile("s_waitcnt vmcnt(0)" ::: "memory");
        __builtin_amdgcn_s_barrier();          // all waves' step-s loads landed
        cfence();                              // ds_reads cannot hoist above

        const int r = s & 3;
        bf16x8 af[4], bfr[4];
        #pragma unroll
        for (int m = 0; m < 4; ++m)
            af[m] = *(const bf16x8*)&As[r][wr * 64 + m * 16 + li][hi * 8];
        #pragma unroll
        for (int n = 0; n < 4; ++n)
            bfr[n] = *(const bf16x8*)&Bs[r][wc * 64 + n * 16 + li][hi * 8];
        #pragma unroll
        for (int m = 0; m < 4; ++m)
            #pragma unroll
            for (int n = 0; n < 4; ++n)
                acc[m][n] = __builtin_amdgcn_mfma_f32_16x16x32_bf16(
                    af[m], bfr[n], acc[m][n], 0, 0, 0);

        cfence();                              // ds_reads cannot sink below
        __builtin_amdgcn_s_barrier();          // releases slot for stage s+4
    }
#undef GSTAGE

    if (MODE == 0 || MODE == 3) trace = tr_s[0] + tr_s[1] + tr_s[2] + tr_s[3];

    if (MODE == 3) {
        const float sc = sqrtf(trace);
        ushort* trib = C + (size_t)b * 32896;
        #pragma unroll
        for (int m = 0; m < 4; ++m)
            #pragma unroll
            for (int n = 0; n < 4; ++n)
                #pragma unroll
                for (int r = 0; r < 4; ++r) {
                    const int gi = i0 + wr * 64 + m * 16 + hi * 4 + r;
                    const int gj = j0 + wc * 64 + n * 16 + li;
                    if (gj <= gi)
                        trib[(gi * (gi + 1)) / 2 + gj] = f2b(acc[m][n][r] * sc);
                }
    } else {
        const float invtr = (MODE == 0) ? (1.0f / trace) : 0.0f;
        ushort* Cb  = ((MODE == 2 && useA2) ? C2 : C) + (size_t)b * 65536;
        ushort* C2b = (MODE == 0) ? (C2 + (size_t)b * 65536) : nullptr;
        #pragma unroll
        for (int m = 0; m < 4; ++m)
            #pragma unroll
            for (int n = 0; n < 4; ++n)
                #pragma unroll
                for (int r = 0; r < 4; ++r) {
                    const int gi = i0 + wr * 64 + m * 16 + hi * 4 + r;
                    const int gj = j0 + wc * 64 + n * 16 + li;
                    const float v = acc[m][n][r];
                    const size_t idx = (size_t)gi * 256 + gj;
                    if (MODE == 0) {
                        float y0 = (v * (1.0f / 196.0f) + ((gi == gj) ? 1e-7f : 0.0f)) * invtr;
                        Cb[idx]  = f2b(y0);
                        C2b[idx] = f2b(((gi == gj) ? 1.5f : 0.0f) - 0.5f * y0);
                    } else if (MODE == 1) {
                        Cb[idx] = f2b(((gi == gj) ? 1.5f : 0.0f) - 0.5f * v);
                    } else {
                        Cb[idx] = f2b(v);
                    }
                }
    }
}

// ---------------------------------------------------------------------------
// FC: partial[split][64][384] = tri[64][K] * W[365][K]^T over this split's K.
// Counted-vmcnt streaming pipeline, 4-deep slab ring, 3 steps in flight,
// cfence-paired barriers, correct tail countdown 9/6/3/0.
// 85 K-splits (510 blocks = 2/CU): 1028 steps of 32 = 8*13 + 77*12.
// ---------------------------------------------------------------------------
__global__ __launch_bounds__(256) void fc_gemm(
    const ushort* __restrict__ tri, const float* __restrict__ W,
    float* __restrict__ partial)
{
    __shared__ ushort Asl[4][64][32];   // 16 KB
    __shared__ float  Wsl[4][64][32];   // 32 KB

    const int ntile = blockIdx.x;              // 0..5
    const int split = blockIdx.y;              // 0..84
    const int steps = 12 + (split < 8 ? 1 : 0);
    const int step0 = split * 12 + (split < 8 ? split : 8);

    const int tid = threadIdx.x, wv = tid >> 6, l = tid & 63;
    const int li = l & 15, hi = l >> 4;

    const int arow = tid >> 2, aseg = tid & 3;            // A: 1 granule/thread
    const int wrow0 = tid >> 3, wseg = tid & 7;           // W: 2 granules/thread
    const int wrow1 = 32 + (tid >> 3);
    const int wcl0 = min(ntile * 64 + wrow0, 364);
    const int wcl1 = min(ntile * 64 + wrow1, 364);

#define FSTAGE(s) do {                                                          \
    const int kk_ = (step0 + (s)) * 32;                                         \
    const int r_ = (s) & 3;                                                     \
    gload16(tri + (size_t)arow * 32896 + kk_ + aseg * 8,                        \
            &Asl[r_][arow][aseg * 8]);                                          \
    gload16(W + (size_t)wcl0 * 32896 + kk_ + wseg * 4,                          \
            &Wsl[r_][wrow0][wseg * 4]);                                         \
    gload16(W + (size_t)wcl1 * 32896 + kk_ + wseg * 4,                          \
            &Wsl[r_][wrow1][wseg * 4]);                                         \
} while (0)

    FSTAGE(0); FSTAGE(1); FSTAGE(2);

    f32x4 acc[4];
    #pragma unroll
    for (int m = 0; m < 4; ++m) acc[m] = (f32x4){0.f, 0.f, 0.f, 0.f};

    for (int s = 0; s < steps; ++s) {
        if (s + 3 < steps) {
            FSTAGE(s + 3);
            asm volatile("s_waitcnt vmcnt(9)" ::: "memory");
        } else if (s + 2 < steps) {
            asm volatile("s_waitcnt vmcnt(6)" ::: "memory");
        } else if (s + 1 < steps) {
            asm volatile("s_waitcnt vmcnt(3)" ::: "memory");
        } else {
            asm volatile("s_waitcnt vmcnt(0)" ::: "memory");
        }
        __builtin_amdgcn_s_barrier();
        cfence();

        const int r = s & 3;
        const float4 wf0 = *(const float4*)&Wsl[r][wv * 16 + li][hi * 8];
        const float4 wf1 = *(const float4*)&Wsl[r][wv * 16 + li][hi * 8 + 4];
        bf16x8 bfr;
        bfr[0] = (short)f2b(wf0.x); bfr[1] = (short)f2b(wf0.y);
        bfr[2] = (short)f2b(wf0.z); bfr[3] = (short)f2b(wf0.w);
        bfr[4] = (short)f2b(wf1.x); bfr[5] = (short)f2b(wf1.y);
        bfr[6] = (short)f2b(wf1.z); bfr[7] = (short)f2b(wf1.w);

        bf16x8 af[4];
        #pragma unroll
        for (int m = 0; m < 4; ++m)
            af[m] = *(const bf16x8*)&Asl[r][m * 16 + li][hi * 8];
        #pragma unroll
        for (int m = 0; m < 4; ++m)
            acc[m] = __builtin_amdgcn_mfma_f32_16x16x32_bf16(af[m], bfr, acc[m], 0, 0, 0);

        cfence();
        __builtin_amdgcn_s_barrier();
    }
#undef FSTAGE

    #pragma unroll
    for (int m = 0; m < 4; ++m)
        #pragma unroll
        for (int rr = 0; rr < 4; ++rr) {
            const int i = m * 16 + hi * 4 + rr;          // batch
            const int j = ntile * 64 + wv * 16 + li;     // class (<384)
            partial[((size_t)split * 64 + i) * 384 + j] = acc[m][rr];
        }
}

__global__ void fc_reduce(const float* __restrict__ partial,
                          const float* __restrict__ bias, float* __restrict__ out)
{
    const int idx = blockIdx.x * 256 + threadIdx.x;
    if (idx >= 64 * 365) return;
    const int b = idx / 365, n = idx % 365;
    float s = bias[n];
    #pragma unroll 5
    for (int sp = 0; sp < 85; ++sp)
        s += partial[((size_t)sp * 64 + b) * 384 + n];
    out[idx] = s;
}

// ---------------------------------------------------------------------------
extern "C" void kernel_launch(void* const* d_in, const int* in_sizes, int n_in,
                              void* d_out, int out_size, void* d_ws, size_t ws_size,
                              hipStream_t stream)
{
    (void)in_sizes; (void)n_in; (void)out_size; (void)ws_size;
    const float* x   = (const float*)d_in[0];
    const float* fcw = (const float*)d_in[1];
    const float* fcb = (const float*)d_in[2];
    float* out = (float*)d_out;
    char* ws = (char*)d_ws;

    const size_t MS = (size_t)64 * 256 * 256 * 2;   // 8 MiB per matrix buffer
    ushort* w0 = (ushort*)(ws + 0 * MS);
    ushort* w1 = (ushort*)(ws + 1 * MS);
    ushort* w2 = (ushort*)(ws + 2 * MS);
    ushort* w3 = (ushort*)(ws + 3 * MS);
    ushort* w4 = (ushort*)(ws + 4 * MS);
    ushort* xc = (ushort*)(ws + 5 * MS);                     // 8 MiB (padded K=256)
    float*  var    = (float*)(ws + 6 * MS);                  // 65,536 B
    ushort* tri    = (ushort*)(ws + 6 * MS + 131072);        // 4,210,688 B
    float*  partial= (float*)(ws + 6 * MS + 131072 + 4210688);  // 8.36 MB

    prep_kernel<<<4096, 256, 0, stream>>>(x, xc, var);

    // cov: Y0 -> w0, T0 -> w1  (Z1 = T0)
    gemm_ns<0><<<256, 256, 0, stream>>>(xc, nullptr, xc, w0, w1, var);
    // Y1 = Y0*T0 -> w2
    gemm_ns<4><<<256, 256, 0, stream>>>(w0, nullptr, w1, w2, nullptr, nullptr);
    // iter2 (Y=w2, Z=w1): T -> w0 ; Y2 -> w3 ; Z2 -> w4
    gemm_ns<1><<<256, 256, 0, stream>>>(w1, nullptr, w2, w0, nullptr, nullptr);
    gemm_ns<2><<<512, 256, 0, stream>>>(w2, w1, w0, w3, w4, nullptr);
    // iter3 (Y=w3, Z=w4): T -> w0 ; Y3 -> w1 ; Z3 -> w2
    gemm_ns<1><<<256, 256, 0, stream>>>(w4, nullptr, w3, w0, nullptr, nullptr);
    gemm_ns<2><<<512, 256, 0, stream>>>(w3, w4, w0, w1, w2, nullptr);
    // iter4 (Y=w1, Z=w2): T -> w0 ; Y4 -> w3 ; Z4 -> w4
    gemm_ns<1><<<256, 256, 0, stream>>>(w2, nullptr, w1, w0, nullptr, nullptr);
    gemm_ns<2><<<512, 256, 0, stream>>>(w1, w2, w0, w3, w4, nullptr);
    // iter5 (Y=w3, Z=w4): T -> w0 ; tri(Y4*T5*sqrt(trace)) -> tri
    gemm_ns<1><<<256, 256, 0, stream>>>(w4, nullptr, w3, w0, nullptr, nullptr);
    gemm_ns<3><<<192, 256, 0, stream>>>(w3, nullptr, w0, tri, nullptr, var);

    fc_gemm<<<dim3(6, 85), 256, 0, stream>>>(tri, fcw, partial);
    fc_reduce<<<(64 * 365 + 255) / 256, 256, 0, stream>>>(partial, fcb, out);
}